// Round 1
// baseline (491.705 us; speedup 1.0000x reference)
//
#include <hip/hip_runtime.h>
#include <hip/hip_bf16.h>

// Problem constants
#define NTOT 262144
#define LDIM 1024
#define DDIM 128
#define FDIM 32
#define NBAGS 256

typedef __attribute__((ext_vector_type(8))) short bf16x8;
typedef __attribute__((ext_vector_type(4))) float f32x4;

__device__ __forceinline__ unsigned short f2b(float f) {
    __hip_bfloat16 h = __float2bfloat16(f);   // RNE
    return __builtin_bit_cast(unsigned short, h);
}
__device__ __forceinline__ float b2f(unsigned short u) {
    union { float f; unsigned int i; } c;
    c.i = ((unsigned int)u) << 16;
    return c.f;
}

// ---------------------------------------------------------------------------
// K0: W1 [1024][128] fp32 -> W1^T [128][1024] bf16 (contiguous K per column)
// ---------------------------------------------------------------------------
__global__ void k_prep(const float* __restrict__ W1, ushort* __restrict__ w1t) {
    int e = blockIdx.x * 256 + threadIdx.x;        // e in [0, 131072)
    if (e >= LDIM * DDIM) return;
    int col = e & 127, k = e >> 7;                 // W1 row-major: e = k*128+col
    w1t[col * 1024 + k] = f2b(W1[e]);
}

// ---------------------------------------------------------------------------
// K1: H = relu(x@W1+b1) -> bf16 Hb;  a = (tanh(HWt+bt)*sigmoid(HWs+bs))@Wa+ba
// 128x128 tile, BK=64, 4 waves (2x2), mfma_f32_16x16x32_bf16
// ---------------------------------------------------------------------------
__global__ __launch_bounds__(256, 2) void k_fused_gemm(
    const float* __restrict__ x, const ushort* __restrict__ w1t,
    const float* __restrict__ b1,
    const float* __restrict__ Wt, const float* __restrict__ bt,
    const float* __restrict__ Ws, const float* __restrict__ bs,
    const float* __restrict__ Wa, const float* __restrict__ ba,
    ushort* __restrict__ Hb, float* __restrict__ aout)
{
    __shared__ __align__(16) ushort sAB[16384];    // 32 KB: A tile | B tile, later sH
    __shared__ __align__(16) float sWt[4096];      // Wt [128][32] fp32
    __shared__ __align__(16) float sWs[4096];      // Ws [128][32] fp32
    __shared__ float sb1[128];
    __shared__ float sbt[32], sbs[32], sWa[32];

    const int t    = threadIdx.x;
    const int lane = t & 63;
    const int wave = t >> 6;
    const int wr   = wave >> 1, wc = wave & 1;     // wave 64x64 sub-tile
    const int lq   = lane >> 4, lr = lane & 15;
    const int row0 = blockIdx.x * 128;

    for (int i = t; i < 4096; i += 256) { sWt[i] = Wt[i]; sWs[i] = Ws[i]; }
    if (t < 128) sb1[t] = b1[t];
    if (t < 32)  { sbt[t] = bt[t]; sbs[t] = bs[t]; sWa[t] = Wa[t]; }

    f32x4 acc[4][4];
#pragma unroll
    for (int m = 0; m < 4; ++m)
#pragma unroll
        for (int n = 0; n < 4; ++n) acc[m][n] = 0;

    const int ar = t >> 1, ah = t & 1;             // staging: row/col = t>>1, half = t&1
    const float*  xsrc = x   + (size_t)(row0 + ar) * LDIM + ah * 32;
    const ushort* bsrc = w1t + (size_t)ar * 1024 + ah * 32;
    char* sA = (char*)sAB;
    char* sB = (char*)sAB + 16384;

    for (int kt = 0; kt < 16; ++kt) {
        // issue global loads before the barrier (latency overlaps the wait)
        float4 av[8];
        const float4* xp = (const float4*)(xsrc + kt * 64);
#pragma unroll
        for (int i = 0; i < 8; ++i) av[i] = xp[i];
        bf16x8 bv[4];
        const bf16x8* bp_ = (const bf16x8*)(bsrc + kt * 64);
#pragma unroll
        for (int i = 0; i < 4; ++i) bv[i] = bp_[i];

        __syncthreads();   // all waves done reading LDS of prev step

#pragma unroll
        for (int c = 0; c < 4; ++c) {
            union { bf16x8 v; ushort u[8]; } pk;
            float4 f0 = av[2 * c], f1 = av[2 * c + 1];
            pk.u[0] = f2b(f0.x); pk.u[1] = f2b(f0.y); pk.u[2] = f2b(f0.z); pk.u[3] = f2b(f0.w);
            pk.u[4] = f2b(f1.x); pk.u[5] = f2b(f1.y); pk.u[6] = f2b(f1.z); pk.u[7] = f2b(f1.w);
            const int cc = ah * 4 + c;             // 16B slot index (k-chunk)
            // XOR swizzle: slot ^= row&7 (row stride 128 B = 8 slots)
            *(bf16x8*)(sA + ar * 128 + ((cc ^ (ar & 7)) << 4)) = pk.v;
            *(bf16x8*)(sB + ar * 128 + ((cc ^ (ar & 7)) << 4)) = bv[c];
        }
        __syncthreads();

#pragma unroll
        for (int kk = 0; kk < 2; ++kk) {
            bf16x8 aF[4], bF[4];
#pragma unroll
            for (int m = 0; m < 4; ++m) {
                int ra = wr * 64 + m * 16 + lr;    // A: row = lane%16
                aF[m] = *(const bf16x8*)(sA + ra * 128 + (((kk * 4 + lq) ^ (ra & 7)) << 4));
            }
#pragma unroll
            for (int n = 0; n < 4; ++n) {
                int cb = wc * 64 + n * 16 + lr;    // B: col = lane%16 (col-major tile)
                bF[n] = *(const bf16x8*)(sB + cb * 128 + (((kk * 4 + lq) ^ (cb & 7)) << 4));
            }
#pragma unroll
            for (int m = 0; m < 4; ++m)
#pragma unroll
                for (int n = 0; n < 4; ++n)
                    acc[m][n] = __builtin_amdgcn_mfma_f32_16x16x32_bf16(aF[m], bF[n], acc[m][n], 0, 0, 0);
        }
    }
    __syncthreads();   // K-loop LDS dead; reuse as sH

    // epilogue: bias + relu, bf16, into swizzled sH [128 rows][256 B], slot ^= row&15
    char* sH = (char*)sAB;
#pragma unroll
    for (int m = 0; m < 4; ++m) {
#pragma unroll
        for (int n = 0; n < 4; ++n) {
            const int colg = wc * 64 + n * 16 + lr;          // C/D: col = lane&15
            const float bias = sb1[colg];
#pragma unroll
            for (int r = 0; r < 4; ++r) {
                const int rowl = wr * 64 + m * 16 + lq * 4 + r; // C/D: row = (lane>>4)*4+reg
                float h = acc[m][n][r] + bias;
                h = fmaxf(h, 0.0f);
                *(ushort*)(sH + rowl * 256 + (((colg >> 3) ^ (rowl & 15)) << 4) + (colg & 7) * 2) = f2b(h);
            }
        }
    }
    __syncthreads();

    // H tile -> global (coalesced, de-swizzle on read)
    ushort* Hg = Hb + (size_t)row0 * 128;
#pragma unroll
    for (int p = 0; p < 8; ++p) {
        int idx = p * 256 + t;
        int row = idx >> 4, slot = idx & 15;
        bf16x8 v = *(const bf16x8*)(sH + row * 256 + ((slot ^ (row & 15)) << 4));
        *(bf16x8*)(Hg + (size_t)row * 128 + slot * 8) = v;
    }

    // score pass: 2 threads per row, each handles 16 of the 32 F-columns
    {
        const int row = t >> 1;
        const int fb  = (t & 1) * 16;
        float at[16], asv[16];
#pragma unroll
        for (int q = 0; q < 16; ++q) { at[q] = 0.f; asv[q] = 0.f; }
        for (int d8 = 0; d8 < 16; ++d8) {
            bf16x8 hv = *(const bf16x8*)(sH + row * 256 + ((d8 ^ (row & 15)) << 4));
#pragma unroll
            for (int j = 0; j < 8; ++j) {
                float h = b2f((unsigned short)hv[j]);
                int d = d8 * 8 + j;
                const float4* wt  = (const float4*)&sWt[d * 32 + fb];
                const float4* wsr = (const float4*)&sWs[d * 32 + fb];
#pragma unroll
                for (int q = 0; q < 4; ++q) {
                    float4 wv = wt[q], sv = wsr[q];
                    at[q * 4 + 0]  += h * wv.x; at[q * 4 + 1]  += h * wv.y;
                    at[q * 4 + 2]  += h * wv.z; at[q * 4 + 3]  += h * wv.w;
                    asv[q * 4 + 0] += h * sv.x; asv[q * 4 + 1] += h * sv.y;
                    asv[q * 4 + 2] += h * sv.z; asv[q * 4 + 3] += h * sv.w;
                }
            }
        }
        float aval = 0.f;
#pragma unroll
        for (int q = 0; q < 16; ++q) {
            float tv  = tanhf(at[q] + sbt[fb + q]);
            float sgm = 1.0f / (1.0f + expf(-(asv[q] + sbs[fb + q])));
            aval += tv * sgm * sWa[fb + q];
        }
        aval += __shfl_xor(aval, 1);
        if ((t & 1) == 0) aout[row0 + row] = aval + ba[0];
    }
}

// ---------------------------------------------------------------------------
// K2: per-bag segment softmax + weighted sum M + projector + L2 normalize
// ---------------------------------------------------------------------------
__global__ __launch_bounds__(256) void k_bag(
    const int* __restrict__ idxs, const float* __restrict__ a,
    const ushort* __restrict__ Hb, const float* __restrict__ Wp,
    const float* __restrict__ bp, float* __restrict__ out)
{
    __shared__ float red[8][128];
    __shared__ float swv[4];
    __shared__ float sM[128];
    __shared__ float sbc[2];

    const int b = blockIdx.x, t = threadIdx.x;

    int start, end;
    {
        int lo = 0, hi = NTOT;
        while (lo < hi) { int m = (lo + hi) >> 1; if (idxs[m] < b) lo = m + 1; else hi = m; }
        start = lo;
        hi = NTOT;
        while (lo < hi) { int m = (lo + hi) >> 1; if (idxs[m] < b + 1) lo = m + 1; else hi = m; }
        end = lo;
    }

    // segment max
    float mx = -3.0e38f;
    for (int i = start + t; i < end; i += 256) mx = fmaxf(mx, a[i]);
#pragma unroll
    for (int m = 1; m < 64; m <<= 1) mx = fmaxf(mx, __shfl_xor(mx, m));
    if ((t & 63) == 0) swv[t >> 6] = mx;
    __syncthreads();
    if (t == 0) sbc[0] = fmaxf(fmaxf(swv[0], swv[1]), fmaxf(swv[2], swv[3]));
    __syncthreads();
    const float amax = sbc[0];

    // segment sum of exp
    float sm = 0.f;
    for (int i = start + t; i < end; i += 256) sm += expf(a[i] - amax);
#pragma unroll
    for (int m = 1; m < 64; m <<= 1) sm += __shfl_xor(sm, m);
    if ((t & 63) == 0) swv[t >> 6] = sm;
    __syncthreads();
    if (t == 0) sbc[1] = swv[0] + swv[1] + swv[2] + swv[3];
    __syncthreads();
    const float den = sbc[1];
    const float inv_den = den > 0.f ? 1.0f / den : 0.0f;

    // weighted accumulate of H rows: 32 col-groups x 8 row-groups
    const int cg = t & 31, rg = t >> 5;
    float a0 = 0, a1 = 0, a2 = 0, a3 = 0;
    for (int i = start + rg; i < end; i += 8) {
        float w = expf(a[i] - amax);
        ushort4 h = *(const ushort4*)(Hb + (size_t)i * 128 + cg * 4);
        a0 += w * b2f(h.x); a1 += w * b2f(h.y); a2 += w * b2f(h.z); a3 += w * b2f(h.w);
    }
    red[rg][cg * 4 + 0] = a0; red[rg][cg * 4 + 1] = a1;
    red[rg][cg * 4 + 2] = a2; red[rg][cg * 4 + 3] = a3;
    __syncthreads();

    if (t < 128) {
        float s = 0.f;
#pragma unroll
        for (int r = 0; r < 8; ++r) s += red[r][t];
        s *= inv_den;
        sM[t] = s;
        out[b * 128 + t] = s;
    }
    __syncthreads();

    // projector + L2 normalize (threads 0..31, all in wave 0)
    if (t < 32) {
        float p = bp[t];
        for (int d = 0; d < 128; ++d) p += sM[d] * Wp[d * 32 + t];
        float ss = p * p;
#pragma unroll
        for (int m = 1; m < 32; m <<= 1) ss += __shfl_xor(ss, m);
        float nrm = sqrtf(ss);
        out[32768 + b * 32 + t] = p / fmaxf(nrm, 1e-12f);
    }
}

// ---------------------------------------------------------------------------
extern "C" void kernel_launch(void* const* d_in, const int* in_sizes, int n_in,
                              void* d_out, int out_size, void* d_ws, size_t ws_size,
                              hipStream_t stream)
{
    const float* x  = (const float*)d_in[0];
    const int*   idxs = (const int*)d_in[1];
    const float* W1 = (const float*)d_in[2];
    const float* b1 = (const float*)d_in[3];
    const float* Wt = (const float*)d_in[4];
    const float* bt = (const float*)d_in[5];
    const float* Ws = (const float*)d_in[6];
    const float* bs = (const float*)d_in[7];
    const float* Wa = (const float*)d_in[8];
    const float* ba = (const float*)d_in[9];
    const float* Wp = (const float*)d_in[10];
    const float* bp = (const float*)d_in[11];
    float* out = (float*)d_out;

    // ws layout: Hb bf16 [N][128] = 64 MB | W1^T bf16 = 256 KB | a fp32 = 1 MB
    char* ws = (char*)d_ws;
    ushort* Hb  = (ushort*)ws;
    ushort* w1t = (ushort*)(ws + 67108864);
    float*  aN  = (float*) (ws + 67108864 + 262144);

    k_prep<<<512, 256, 0, stream>>>(W1, w1t);
    k_fused_gemm<<<2048, 256, 0, stream>>>(x, w1t, b1, Wt, bt, Ws, bs, Wa, ba, Hb, aN);
    k_bag<<<NBAGS, 256, 0, stream>>>(idxs, aN, Hb, Wp, bp, out);
}

// Round 3
// 331.096 us; speedup vs baseline: 1.4851x; 1.4851x over previous
//
#include <hip/hip_runtime.h>
#include <hip/hip_bf16.h>

// Problem constants
#define NTOT 262144
#define LDIM 1024
#define DDIM 128
#define FDIM 32
#define NBAGS 256

typedef __attribute__((ext_vector_type(8))) short bf16x8;
typedef __attribute__((ext_vector_type(4))) float f32x4;

__device__ __forceinline__ unsigned short f2b(float f) {
    __hip_bfloat16 h = __float2bfloat16(f);   // RNE
    return __builtin_bit_cast(unsigned short, h);
}
__device__ __forceinline__ float b2f(unsigned short u) {
    union { float f; unsigned int i; } c;
    c.i = ((unsigned int)u) << 16;
    return c.f;
}

// ---------------------------------------------------------------------------
// K0: W1 [1024][128] fp32 -> W1^T [128][1024] bf16 (contiguous K per column)
// ---------------------------------------------------------------------------
__global__ void k_prep(const float* __restrict__ W1, ushort* __restrict__ w1t) {
    int e = blockIdx.x * 256 + threadIdx.x;        // e in [0, 131072)
    if (e >= LDIM * DDIM) return;
    int col = e & 127, k = e >> 7;                 // W1 row-major: e = k*128+col
    w1t[col * 1024 + k] = f2b(W1[e]);
}

// ---------------------------------------------------------------------------
// K1: H = relu(x@W1+b1) -> bf16 Hb;  a = (tanh(HWt+bt)*sigmoid(HWs+bs))@Wa+ba
// 128x128 tile, BK=64, 4 waves (2x2), mfma_f32_16x16x32_bf16
// Pipelined: loads for kt+1 issued after staging barrier -> in flight during
// the MFMA phase, complete by the next iteration's vmcnt(0) drain.
// Score pass via MFMA from LDS-resident bf16 H and bf16 Wt^T/Ws^T.
// ---------------------------------------------------------------------------
__global__ __launch_bounds__(256, 3) void k_fused_gemm(
    const float* __restrict__ x, const ushort* __restrict__ w1t,
    const float* __restrict__ b1,
    const float* __restrict__ Wt, const float* __restrict__ bt,
    const float* __restrict__ Ws, const float* __restrict__ bs,
    const float* __restrict__ Wa, const float* __restrict__ ba,
    ushort* __restrict__ Hb, float* __restrict__ aout)
{
    __shared__ __align__(16) ushort sAB[16384];    // 32 KB: A tile | B tile, later sH
    __shared__ __align__(16) ushort sWtT[4096];    // Wt^T [32 f][128 d] bf16, swizzled
    __shared__ __align__(16) ushort sWsT[4096];    // Ws^T bf16, swizzled
    __shared__ float sb1[128];
    __shared__ float sbt[32], sbs[32], sWa[32];

    const int t    = threadIdx.x;
    const int lane = t & 63;
    const int wave = t >> 6;
    const int wr   = wave >> 1, wc = wave & 1;     // wave 64x64 sub-tile
    const int lq   = lane >> 4, lr = lane & 15;
    const int row0 = blockIdx.x * 128;

    // stage Wt^T / Ws^T as swizzled bf16 (once per block)
    for (int e = t; e < 4096; e += 256) {
        int d = e >> 5, f = e & 31;                // Wt row-major: e = d*32+f
        int byt = f * 256 + ((((d >> 3) ^ (f & 15))) << 4) + (d & 7) * 2;
        *(ushort*)((char*)sWtT + byt) = f2b(Wt[e]);
        *(ushort*)((char*)sWsT + byt) = f2b(Ws[e]);
    }
    if (t < 128) sb1[t] = b1[t];
    if (t < 32)  { sbt[t] = bt[t]; sbs[t] = bs[t]; sWa[t] = Wa[t]; }
    const float ba0 = ba[0];

    f32x4 acc[4][4];
#pragma unroll
    for (int m = 0; m < 4; ++m)
#pragma unroll
        for (int n = 0; n < 4; ++n) acc[m][n] = 0;

    const int ar = t >> 1, ah = t & 1;             // staging: row/col = t>>1, half = t&1
    const float*  xsrc = x   + (size_t)(row0 + ar) * LDIM + ah * 32;
    const ushort* bsrc = w1t + (size_t)ar * 1024 + ah * 32;
    char* sA = (char*)sAB;
    char* sB = (char*)sAB + 16384;

    // prologue: load tile kt=0 into registers
    float4 av[8];
    bf16x8 bv[4];
    {
        const float4* xp = (const float4*)(xsrc);
#pragma unroll
        for (int i = 0; i < 8; ++i) av[i] = xp[i];
        const bf16x8* bp_ = (const bf16x8*)(bsrc);
#pragma unroll
        for (int i = 0; i < 4; ++i) bv[i] = bp_[i];
    }

    for (int kt = 0; kt < 16; ++kt) {
        __syncthreads();   // all waves done reading LDS of prev step; loads(kt) drained

        // stage registers -> LDS (fp32 -> bf16 for A)
#pragma unroll
        for (int c = 0; c < 4; ++c) {
            union { bf16x8 v; ushort u[8]; } pk;
            float4 f0 = av[2 * c], f1 = av[2 * c + 1];
            pk.u[0] = f2b(f0.x); pk.u[1] = f2b(f0.y); pk.u[2] = f2b(f0.z); pk.u[3] = f2b(f0.w);
            pk.u[4] = f2b(f1.x); pk.u[5] = f2b(f1.y); pk.u[6] = f2b(f1.z); pk.u[7] = f2b(f1.w);
            const int cc = ah * 4 + c;             // 16B slot index (k-chunk)
            // XOR swizzle: slot ^= row&7 (row stride 128 B = 8 slots)
            *(bf16x8*)(sA + ar * 128 + ((cc ^ (ar & 7)) << 4)) = pk.v;
            *(bf16x8*)(sB + ar * 128 + ((cc ^ (ar & 7)) << 4)) = bv[c];
        }
        __syncthreads();

        // issue loads for kt+1: they stay in flight during the MFMA phase
        if (kt < 15) {
            const float4* xp = (const float4*)(xsrc + (kt + 1) * 64);
#pragma unroll
            for (int i = 0; i < 8; ++i) av[i] = xp[i];
            const bf16x8* bp_ = (const bf16x8*)(bsrc + (kt + 1) * 64);
#pragma unroll
            for (int i = 0; i < 4; ++i) bv[i] = bp_[i];
        }

#pragma unroll
        for (int kk = 0; kk < 2; ++kk) {
            bf16x8 aF[4], bF[4];
#pragma unroll
            for (int m = 0; m < 4; ++m) {
                int ra = wr * 64 + m * 16 + lr;    // A: row = lane%16
                aF[m] = *(const bf16x8*)(sA + ra * 128 + (((kk * 4 + lq) ^ (ra & 7)) << 4));
            }
#pragma unroll
            for (int n = 0; n < 4; ++n) {
                int cb = wc * 64 + n * 16 + lr;    // B: col = lane%16 (col-major tile)
                bF[n] = *(const bf16x8*)(sB + cb * 128 + (((kk * 4 + lq) ^ (cb & 7)) << 4));
            }
#pragma unroll
            for (int m = 0; m < 4; ++m)
#pragma unroll
                for (int n = 0; n < 4; ++n)
                    acc[m][n] = __builtin_amdgcn_mfma_f32_16x16x32_bf16(aF[m], bF[n], acc[m][n], 0, 0, 0);
        }
    }
    __syncthreads();   // K-loop LDS dead; reuse as sH

    // epilogue: bias + relu, bf16, into swizzled sH [128 rows][256 B], slot ^= row&15
    char* sH = (char*)sAB;
#pragma unroll
    for (int m = 0; m < 4; ++m) {
#pragma unroll
        for (int n = 0; n < 4; ++n) {
            const int colg = wc * 64 + n * 16 + lr;          // C/D: col = lane&15
            const float bias = sb1[colg];
#pragma unroll
            for (int r = 0; r < 4; ++r) {
                const int rowl = wr * 64 + m * 16 + lq * 4 + r; // C/D: row = (lane>>4)*4+reg
                float h = acc[m][n][r] + bias;
                h = fmaxf(h, 0.0f);
                *(ushort*)(sH + rowl * 256 + (((colg >> 3) ^ (rowl & 15)) << 4) + (colg & 7) * 2) = f2b(h);
            }
        }
    }
    __syncthreads();

    // H tile -> global (coalesced, de-swizzle on read)
    ushort* Hg = Hb + (size_t)row0 * 128;
#pragma unroll
    for (int p = 0; p < 8; ++p) {
        int idx = p * 256 + t;
        int row = idx >> 4, slot = idx & 15;
        bf16x8 v = *(const bf16x8*)(sH + row * 256 + ((slot ^ (row & 15)) << 4));
        *(bf16x8*)(Hg + (size_t)row * 128 + slot * 8) = v;
    }

    // ---- score pass via MFMA: each wave owns 32 rows (wave*32 .. wave*32+31)
    // At[r][f] = sum_d H[r][d] Wt[d][f] ; As likewise. 32 MFMAs per wave.
    {
        f32x4 at_[2][2], as_[2][2];
#pragma unroll
        for (int m = 0; m < 2; ++m)
#pragma unroll
            for (int n = 0; n < 2; ++n) { at_[m][n] = 0; as_[m][n] = 0; }

        const char* cWtT = (const char*)sWtT;
        const char* cWsT = (const char*)sWsT;
#pragma unroll
        for (int kk = 0; kk < 4; ++kk) {
            bf16x8 aH[2], bT[2], bS[2];
            const int slot = kk * 4 + lq;
#pragma unroll
            for (int m = 0; m < 2; ++m) {
                const int ra = wave * 32 + m * 16 + lr;
                aH[m] = *(const bf16x8*)(sH + ra * 256 + ((slot ^ (ra & 15)) << 4));
            }
#pragma unroll
            for (int n = 0; n < 2; ++n) {
                const int f = n * 16 + lr;
                bT[n] = *(const bf16x8*)(cWtT + f * 256 + ((slot ^ (f & 15)) << 4));
                bS[n] = *(const bf16x8*)(cWsT + f * 256 + ((slot ^ (f & 15)) << 4));
            }
#pragma unroll
            for (int m = 0; m < 2; ++m)
#pragma unroll
                for (int n = 0; n < 2; ++n) {
                    at_[m][n] = __builtin_amdgcn_mfma_f32_16x16x32_bf16(aH[m], bT[n], at_[m][n], 0, 0, 0);
                    as_[m][n] = __builtin_amdgcn_mfma_f32_16x16x32_bf16(aH[m], bS[n], as_[m][n], 0, 0, 0);
                }
        }

        // gated combine + row-reduce over 32 F-cols
#pragma unroll
        for (int m = 0; m < 2; ++m) {
#pragma unroll
            for (int r = 0; r < 4; ++r) {
                float s = 0.f;
#pragma unroll
                for (int n = 0; n < 2; ++n) {
                    const int f = n * 16 + lr;
                    float tv = tanhf(at_[m][n][r] + sbt[f]);
                    float sg = 1.0f / (1.0f + __expf(-(as_[m][n][r] + sbs[f])));
                    s += tv * sg * sWa[f];
                }
                s += __shfl_xor(s, 1);
                s += __shfl_xor(s, 2);
                s += __shfl_xor(s, 4);
                s += __shfl_xor(s, 8);
                if (lr == 0)
                    aout[row0 + wave * 32 + m * 16 + lq * 4 + r] = s + ba0;
            }
        }
    }
}

// ---------------------------------------------------------------------------
// K2: per-bag segment softmax + weighted sum M + projector + L2 normalize
// 1024 threads/block (16 waves) for latency hiding; 16 B/lane Hb loads.
// ---------------------------------------------------------------------------
__global__ __launch_bounds__(1024) void k_bag(
    const int* __restrict__ idxs, const float* __restrict__ a,
    const ushort* __restrict__ Hb, const float* __restrict__ Wp,
    const float* __restrict__ bp, float* __restrict__ out)
{
    __shared__ float red[64 * 132];     // padded stride 132 to spread banks
    __shared__ float swv[16];
    __shared__ float sM[128];
    __shared__ float sbc[2];

    const int b = blockIdx.x, t = threadIdx.x;
    const int lane = t & 63, wave = t >> 6;

    int start, end;
    {
        int lo = 0, hi = NTOT;
        while (lo < hi) { int m = (lo + hi) >> 1; if (idxs[m] < b) lo = m + 1; else hi = m; }
        start = lo;
        hi = NTOT;
        while (lo < hi) { int m = (lo + hi) >> 1; if (idxs[m] < b + 1) lo = m + 1; else hi = m; }
        end = lo;
    }

    // segment max
    float mx = -3.0e38f;
    for (int i = start + t; i < end; i += 1024) mx = fmaxf(mx, a[i]);
#pragma unroll
    for (int m = 1; m < 64; m <<= 1) mx = fmaxf(mx, __shfl_xor(mx, m));
    if (lane == 0) swv[wave] = mx;
    __syncthreads();
    if (t == 0) {
        float v = swv[0];
#pragma unroll
        for (int i = 1; i < 16; ++i) v = fmaxf(v, swv[i]);
        sbc[0] = v;
    }
    __syncthreads();
    const float amax = sbc[0];

    // segment sum of exp
    float sm = 0.f;
    for (int i = start + t; i < end; i += 1024) sm += __expf(a[i] - amax);
#pragma unroll
    for (int m = 1; m < 64; m <<= 1) sm += __shfl_xor(sm, m);
    if (lane == 0) swv[wave] = sm;
    __syncthreads();
    if (t == 0) {
        float v = 0.f;
#pragma unroll
        for (int i = 0; i < 16; ++i) v += swv[i];
        sbc[1] = v;
    }
    __syncthreads();
    const float den = sbc[1];
    const float inv_den = den > 0.f ? 1.0f / den : 0.0f;

    // weighted accumulate of H rows: 16 col-groups (16B each) x 64 row-groups
    const int cg = t & 15, rg = t >> 4;
    float acc[8];
#pragma unroll
    for (int j = 0; j < 8; ++j) acc[j] = 0.f;
    for (int i = start + rg; i < end; i += 64) {
        float w = __expf(a[i] - amax);
        bf16x8 h = *(const bf16x8*)(Hb + (size_t)i * 128 + cg * 8);
#pragma unroll
        for (int j = 0; j < 8; ++j) acc[j] += w * b2f((unsigned short)h[j]);
    }
#pragma unroll
    for (int j = 0; j < 8; ++j) red[rg * 132 + cg * 8 + j] = acc[j];
    __syncthreads();

    if (t < 128) {
        float s = 0.f;
        for (int r = 0; r < 64; ++r) s += red[r * 132 + t];
        s *= inv_den;
        sM[t] = s;
        out[b * 128 + t] = s;
    }
    __syncthreads();

    // projector + L2 normalize (threads 0..31, all in wave 0)
    if (t < 32) {
        float p = bp[t];
        for (int d = 0; d < 128; ++d) p += sM[d] * Wp[d * 32 + t];
        float ss = p * p;
#pragma unroll
        for (int m = 1; m < 32; m <<= 1) ss += __shfl_xor(ss, m);
        float nrm = sqrtf(ss);
        out[32768 + b * 32 + t] = p / fmaxf(nrm, 1e-12f);
    }
}

// ---------------------------------------------------------------------------
extern "C" void kernel_launch(void* const* d_in, const int* in_sizes, int n_in,
                              void* d_out, int out_size, void* d_ws, size_t ws_size,
                              hipStream_t stream)
{
    const float* x  = (const float*)d_in[0];
    const int*   idxs = (const int*)d_in[1];
    const float* W1 = (const float*)d_in[2];
    const float* b1 = (const float*)d_in[3];
    const float* Wt = (const float*)d_in[4];
    const float* bt = (const float*)d_in[5];
    const float* Ws = (const float*)d_in[6];
    const float* bs = (const float*)d_in[7];
    const float* Wa = (const float*)d_in[8];
    const float* ba = (const float*)d_in[9];
    const float* Wp = (const float*)d_in[10];
    const float* bp = (const float*)d_in[11];
    float* out = (float*)d_out;

    // ws layout: Hb bf16 [N][128] = 64 MB | W1^T bf16 = 256 KB | a fp32 = 1 MB
    char* ws = (char*)d_ws;
    ushort* Hb  = (ushort*)ws;
    ushort* w1t = (ushort*)(ws + 67108864);
    float*  aN  = (float*) (ws + 67108864 + 262144);

    k_prep<<<512, 256, 0, stream>>>(W1, w1t);
    k_fused_gemm<<<2048, 256, 0, stream>>>(x, w1t, b1, Wt, bt, Ws, bs, Wa, ba, Hb, aN);
    k_bag<<<NBAGS, 1024, 0, stream>>>(idxs, aN, Hb, Wp, bp, out);
}

// Round 4
// 265.941 us; speedup vs baseline: 1.8489x; 1.2450x over previous
//
#include <hip/hip_runtime.h>
#include <hip/hip_bf16.h>

// Problem constants
#define NTOT 262144
#define LDIM 1024
#define DDIM 128
#define FDIM 32
#define NBAGS 256

typedef __attribute__((ext_vector_type(8))) short bf16x8;
typedef __attribute__((ext_vector_type(4))) float f32x4;

__device__ __forceinline__ unsigned short f2b(float f) {
    __hip_bfloat16 h = __float2bfloat16(f);   // RNE
    return __builtin_bit_cast(unsigned short, h);
}
__device__ __forceinline__ float b2f(unsigned short u) {
    union { float f; unsigned int i; } c;
    c.i = ((unsigned int)u) << 16;
    return c.f;
}

// ---------------------------------------------------------------------------
// K0: (a) W1 [1024][128] fp32 -> w1t2: kt-tiled, PRE-SWIZZLED bf16 layout.
//     Data (col, k) with kt=k>>6, ko=k&63, cc=ko>>3, kr=ko&7 lands at
//     w1t2[kt*8192 + col*64 + (cc^(col&7))*8 + kr]. GEMM stages it with a
//     LINEAR copy; the MFMA read-side XOR undoes the pre-swizzle.
//     (b) bag_start scan over sorted idxs (removes per-block binary search).
// ---------------------------------------------------------------------------
__global__ void k_prep(const float* __restrict__ W1, const int* __restrict__ idxs,
                       ushort* __restrict__ w1t2, int* __restrict__ bag_start) {
    int gid = blockIdx.x * 256 + threadIdx.x;          // grid covers NTOT
    if (gid < LDIM * DDIM) {
        int col = gid & 127, k = gid >> 7;             // W1 row-major: gid = k*128+col
        int kt = k >> 6, ko = k & 63;
        int cc = ko >> 3, kr = ko & 7;
        int ccs = cc ^ (col & 7);
        w1t2[kt * 8192 + col * 64 + ccs * 8 + kr] = f2b(W1[gid]);
    }
    if (gid < NTOT) {
        int v = idxs[gid];
        int p = (gid == 0) ? -1 : idxs[gid - 1];
        for (int b = p + 1; b <= v; ++b) bag_start[b] = gid;
        if (gid == NTOT - 1)
            for (int b = v + 1; b <= NBAGS; ++b) bag_start[b] = NTOT;
    }
}

// ---------------------------------------------------------------------------
// K1: H = relu(x@W1+b1) -> bf16 Hb;  a = (tanh(HWt+bt)*sigmoid(HWs+bs))@Wa+ba
// 128x128 tile, BK=64, 4 waves (2x2), mfma_f32_16x16x32_bf16.
// Linear-contiguous global staging (1KB/instr A, 4KB/instr B), software
// pipelined by one K-step. Score pass via MFMA from LDS-resident bf16 H.
// ---------------------------------------------------------------------------
__global__ __launch_bounds__(256, 3) void k_fused_gemm(
    const float* __restrict__ x, const ushort* __restrict__ w1t2,
    const float* __restrict__ b1,
    const float* __restrict__ Wt, const float* __restrict__ bt,
    const float* __restrict__ Ws, const float* __restrict__ bs,
    const float* __restrict__ Wa, const float* __restrict__ ba,
    ushort* __restrict__ Hb, float* __restrict__ aout)
{
    __shared__ __align__(16) ushort sAB[16384];    // 32 KB: A tile | B tile, later sH
    __shared__ __align__(16) ushort sWtT[4096];    // Wt^T [32 f][128 d] bf16, swizzled
    __shared__ __align__(16) ushort sWsT[4096];    // Ws^T bf16, swizzled
    __shared__ float sb1[128];
    __shared__ float sbt[32], sbs[32], sWa[32];

    const int t    = threadIdx.x;
    const int lane = t & 63;
    const int wave = t >> 6;
    const int wr   = wave >> 1, wc = wave & 1;     // wave 64x64 sub-tile
    const int lq   = lane >> 4, lr = lane & 15;
    const int row0 = blockIdx.x * 128;

    // stage Wt^T / Ws^T as swizzled bf16 (once per block)
    for (int e = t; e < 4096; e += 256) {
        int d = e >> 5, f = e & 31;                // Wt row-major: e = d*32+f
        int byt = f * 256 + ((((d >> 3) ^ (f & 15))) << 4) + (d & 7) * 2;
        *(ushort*)((char*)sWtT + byt) = f2b(Wt[e]);
        *(ushort*)((char*)sWsT + byt) = f2b(Ws[e]);
    }
    if (t < 128) sb1[t] = b1[t];
    if (t < 32)  { sbt[t] = bt[t]; sbs[t] = bs[t]; sWa[t] = Wa[t]; }
    const float ba0 = ba[0];

    f32x4 acc[4][4];
#pragma unroll
    for (int m = 0; m < 4; ++m)
#pragma unroll
        for (int n = 0; n < 4; ++n) acc[m][n] = 0;

    char* sA = (char*)sAB;
    char* sB = (char*)sAB + 16384;

    // ---- linear staging geometry ----
    // A: thread (t, j) loads float4 at x[(row0+arow+16j)*1024 + kt*64 + acol4]
    //    -> 4 bf16 at sA[(arow+16j)*128 + ((acc_^rowlow)<<4) + aoff]
    //    (16j doesn't change row&7, so the swizzled column byte is j-invariant)
    const int arow  = t >> 4;                  // 0..15
    const int acol4 = (t & 15) * 4;            // fp32 col 0..60
    const float* xb = x + (size_t)(row0 + arow) * LDIM + acol4;
    const int a_base = (((acol4 >> 3) ^ (arow & 7)) << 4) + (acol4 & 7) * 2;
    // B: pure linear copy; chunk = t + 256*jj -> 16 B
    const ushort* bb = w1t2 + t * 8;
    char* sBw = sB + t * 16;

    // prologue: load tile kt=0 into registers
    float4 av[8];
    bf16x8 bv[4];
#pragma unroll
    for (int j = 0; j < 8; ++j) av[j] = *(const float4*)(xb + j * (16 * LDIM));
#pragma unroll
    for (int jj = 0; jj < 4; ++jj) bv[jj] = *(const bf16x8*)(bb + jj * 2048);

    for (int kt = 0; kt < 16; ++kt) {
        __syncthreads();   // all waves done reading LDS of prev step

        // stage registers -> LDS (fp32 -> bf16 for A; B is a linear copy)
#pragma unroll
        for (int j = 0; j < 8; ++j) {
            float4 f = av[j];
            uint2 pk;
            pk.x = (unsigned)f2b(f.x) | ((unsigned)f2b(f.y) << 16);
            pk.y = (unsigned)f2b(f.z) | ((unsigned)f2b(f.w) << 16);
            *(uint2*)(sA + (arow + 16 * j) * 128 + a_base) = pk;
        }
#pragma unroll
        for (int jj = 0; jj < 4; ++jj)
            *(bf16x8*)(sBw + jj * 4096) = bv[jj];
        __syncthreads();

        // issue loads for kt+1: in flight during the MFMA phase
        if (kt < 15) {
            const float* xk = xb + (kt + 1) * 64;
#pragma unroll
            for (int j = 0; j < 8; ++j) av[j] = *(const float4*)(xk + j * (16 * LDIM));
            const ushort* bk = bb + (kt + 1) * 8192;
#pragma unroll
            for (int jj = 0; jj < 4; ++jj) bv[jj] = *(const bf16x8*)(bk + jj * 2048);
        }

#pragma unroll
        for (int kk = 0; kk < 2; ++kk) {
            bf16x8 aF[4], bF[4];
#pragma unroll
            for (int m = 0; m < 4; ++m) {
                int ra = wr * 64 + m * 16 + lr;    // A: row = lane%16
                aF[m] = *(const bf16x8*)(sA + ra * 128 + (((kk * 4 + lq) ^ (ra & 7)) << 4));
            }
#pragma unroll
            for (int n = 0; n < 4; ++n) {
                int cb = wc * 64 + n * 16 + lr;    // B: col = lane%16
                bF[n] = *(const bf16x8*)(sB + cb * 128 + (((kk * 4 + lq) ^ (cb & 7)) << 4));
            }
#pragma unroll
            for (int m = 0; m < 4; ++m)
#pragma unroll
                for (int n = 0; n < 4; ++n)
                    acc[m][n] = __builtin_amdgcn_mfma_f32_16x16x32_bf16(aF[m], bF[n], acc[m][n], 0, 0, 0);
        }
    }
    __syncthreads();   // K-loop LDS dead; reuse as sH

    // epilogue: bias + relu, bf16, into swizzled sH [128 rows][256 B], slot ^= row&15
    char* sH = (char*)sAB;
#pragma unroll
    for (int m = 0; m < 4; ++m) {
#pragma unroll
        for (int n = 0; n < 4; ++n) {
            const int colg = wc * 64 + n * 16 + lr;          // C/D: col = lane&15
            const float bias = sb1[colg];
#pragma unroll
            for (int r = 0; r < 4; ++r) {
                const int rowl = wr * 64 + m * 16 + lq * 4 + r; // C/D: row = (lane>>4)*4+reg
                float h = acc[m][n][r] + bias;
                h = fmaxf(h, 0.0f);
                *(ushort*)(sH + rowl * 256 + (((colg >> 3) ^ (rowl & 15)) << 4) + (colg & 7) * 2) = f2b(h);
            }
        }
    }
    __syncthreads();

    // H tile -> global (coalesced, de-swizzle on read)
    ushort* Hg = Hb + (size_t)row0 * 128;
#pragma unroll
    for (int p = 0; p < 8; ++p) {
        int idx = p * 256 + t;
        int row = idx >> 4, slot = idx & 15;
        bf16x8 v = *(const bf16x8*)(sH + row * 256 + ((slot ^ (row & 15)) << 4));
        *(bf16x8*)(Hg + (size_t)row * 128 + slot * 8) = v;
    }

    // ---- score pass via MFMA: each wave owns 32 rows (wave*32 .. wave*32+31)
    {
        f32x4 at_[2][2], as_[2][2];
#pragma unroll
        for (int m = 0; m < 2; ++m)
#pragma unroll
            for (int n = 0; n < 2; ++n) { at_[m][n] = 0; as_[m][n] = 0; }

        const char* cWtT = (const char*)sWtT;
        const char* cWsT = (const char*)sWsT;
#pragma unroll
        for (int kk = 0; kk < 4; ++kk) {
            bf16x8 aH[2], bT[2], bS[2];
            const int slot = kk * 4 + lq;
#pragma unroll
            for (int m = 0; m < 2; ++m) {
                const int ra = wave * 32 + m * 16 + lr;
                aH[m] = *(const bf16x8*)(sH + ra * 256 + ((slot ^ (ra & 15)) << 4));
            }
#pragma unroll
            for (int n = 0; n < 2; ++n) {
                const int f = n * 16 + lr;
                bT[n] = *(const bf16x8*)(cWtT + f * 256 + ((slot ^ (f & 15)) << 4));
                bS[n] = *(const bf16x8*)(cWsT + f * 256 + ((slot ^ (f & 15)) << 4));
            }
#pragma unroll
            for (int m = 0; m < 2; ++m)
#pragma unroll
                for (int n = 0; n < 2; ++n) {
                    at_[m][n] = __builtin_amdgcn_mfma_f32_16x16x32_bf16(aH[m], bT[n], at_[m][n], 0, 0, 0);
                    as_[m][n] = __builtin_amdgcn_mfma_f32_16x16x32_bf16(aH[m], bS[n], as_[m][n], 0, 0, 0);
                }
        }

        // gated combine + row-reduce over 32 F-cols
#pragma unroll
        for (int m = 0; m < 2; ++m) {
#pragma unroll
            for (int r = 0; r < 4; ++r) {
                float s = 0.f;
#pragma unroll
                for (int n = 0; n < 2; ++n) {
                    const int f = n * 16 + lr;
                    float tv = tanhf(at_[m][n][r] + sbt[f]);
                    float sg = 1.0f / (1.0f + __expf(-(as_[m][n][r] + sbs[f])));
                    s += tv * sg * sWa[f];
                }
                s += __shfl_xor(s, 1);
                s += __shfl_xor(s, 2);
                s += __shfl_xor(s, 4);
                s += __shfl_xor(s, 8);
                if (lr == 0)
                    aout[row0 + wave * 32 + m * 16 + lq * 4 + r] = s + ba0;
            }
        }
    }
}

// ---------------------------------------------------------------------------
// K2: per-bag segment softmax + weighted sum M + projector + L2 normalize
// 1024 threads/block (16 waves); bag bounds precomputed (no binary search).
// ---------------------------------------------------------------------------
__global__ __launch_bounds__(1024) void k_bag(
    const int* __restrict__ bag_start, const float* __restrict__ a,
    const ushort* __restrict__ Hb, const float* __restrict__ Wp,
    const float* __restrict__ bp, float* __restrict__ out)
{
    __shared__ float red[64 * 132];     // padded stride 132 to spread banks
    __shared__ float swv[16];
    __shared__ float sM[128];
    __shared__ float sbc[2];

    const int b = blockIdx.x, t = threadIdx.x;
    const int lane = t & 63, wave = t >> 6;

    const int start = bag_start[b];
    const int end   = bag_start[b + 1];

    // segment max
    float mx = -3.0e38f;
    for (int i = start + t; i < end; i += 1024) mx = fmaxf(mx, a[i]);
#pragma unroll
    for (int m = 1; m < 64; m <<= 1) mx = fmaxf(mx, __shfl_xor(mx, m));
    if (lane == 0) swv[wave] = mx;
    __syncthreads();
    if (t == 0) {
        float v = swv[0];
#pragma unroll
        for (int i = 1; i < 16; ++i) v = fmaxf(v, swv[i]);
        sbc[0] = v;
    }
    __syncthreads();
    const float amax = sbc[0];

    // segment sum of exp
    float sm = 0.f;
    for (int i = start + t; i < end; i += 1024) sm += __expf(a[i] - amax);
#pragma unroll
    for (int m = 1; m < 64; m <<= 1) sm += __shfl_xor(sm, m);
    if (lane == 0) swv[wave] = sm;
    __syncthreads();
    if (t == 0) {
        float v = 0.f;
#pragma unroll
        for (int i = 0; i < 16; ++i) v += swv[i];
        sbc[1] = v;
    }
    __syncthreads();
    const float den = sbc[1];
    const float inv_den = den > 0.f ? 1.0f / den : 0.0f;

    // weighted accumulate of H rows: 16 col-groups (16B each) x 64 row-groups
    const int cg = t & 15, rg = t >> 4;
    float acc[8];
#pragma unroll
    for (int j = 0; j < 8; ++j) acc[j] = 0.f;
    for (int i = start + rg; i < end; i += 64) {
        float w = __expf(a[i] - amax);
        bf16x8 h = *(const bf16x8*)(Hb + (size_t)i * 128 + cg * 8);
#pragma unroll
        for (int j = 0; j < 8; ++j) acc[j] += w * b2f((unsigned short)h[j]);
    }
#pragma unroll
    for (int j = 0; j < 8; ++j) red[rg * 132 + cg * 8 + j] = acc[j];
    __syncthreads();

    if (t < 128) {
        float s = 0.f;
        for (int r = 0; r < 64; ++r) s += red[r * 132 + t];
        s *= inv_den;
        sM[t] = s;
        out[b * 128 + t] = s;
    }
    __syncthreads();

    // projector + L2 normalize (threads 0..31, all in wave 0)
    if (t < 32) {
        float p = bp[t];
        for (int d = 0; d < 128; ++d) p += sM[d] * Wp[d * 32 + t];
        float ss = p * p;
#pragma unroll
        for (int m = 1; m < 32; m <<= 1) ss += __shfl_xor(ss, m);
        float nrm = sqrtf(ss);
        out[32768 + b * 32 + t] = p / fmaxf(nrm, 1e-12f);
    }
}

// ---------------------------------------------------------------------------
extern "C" void kernel_launch(void* const* d_in, const int* in_sizes, int n_in,
                              void* d_out, int out_size, void* d_ws, size_t ws_size,
                              hipStream_t stream)
{
    const float* x  = (const float*)d_in[0];
    const int*   idxs = (const int*)d_in[1];
    const float* W1 = (const float*)d_in[2];
    const float* b1 = (const float*)d_in[3];
    const float* Wt = (const float*)d_in[4];
    const float* bt = (const float*)d_in[5];
    const float* Ws = (const float*)d_in[6];
    const float* bs = (const float*)d_in[7];
    const float* Wa = (const float*)d_in[8];
    const float* ba = (const float*)d_in[9];
    const float* Wp = (const float*)d_in[10];
    const float* bp = (const float*)d_in[11];
    float* out = (float*)d_out;

    // ws layout: Hb bf16 [N][128] = 64 MB | w1t2 bf16 256 KB | a fp32 1 MB | bag_start
    char* ws = (char*)d_ws;
    ushort* Hb   = (ushort*)ws;
    ushort* w1t2 = (ushort*)(ws + 67108864);
    float*  aN   = (float*) (ws + 67108864 + 262144);
    int*    bagS = (int*)   (ws + 67108864 + 262144 + 1048576);

    k_prep<<<1024, 256, 0, stream>>>(W1, idxs, w1t2, bagS);
    k_fused_gemm<<<2048, 256, 0, stream>>>(x, w1t2, b1, Wt, bt, Ws, bs, Wa, ba, Hb, aN);
    k_bag<<<NBAGS, 1024, 0, stream>>>(bagS, aN, Hb, Wp, bp, out);
}

// Round 5
// 231.795 us; speedup vs baseline: 2.1213x; 1.1473x over previous
//
#include <hip/hip_runtime.h>
#include <hip/hip_bf16.h>

// Problem constants
#define NTOT 262144
#define LDIM 1024
#define DDIM 128
#define FDIM 32
#define NBAGS 256

typedef __attribute__((ext_vector_type(8))) short bf16x8;
typedef __attribute__((ext_vector_type(4))) float f32x4;

__device__ __forceinline__ unsigned short f2b(float f) {
    __hip_bfloat16 h = __float2bfloat16(f);   // RNE
    return __builtin_bit_cast(unsigned short, h);
}
__device__ __forceinline__ float b2f(unsigned short u) {
    union { float f; unsigned int i; } c;
    c.i = ((unsigned int)u) << 16;
    return c.f;
}

// ---------------------------------------------------------------------------
// K0: (a) W1 [1024][128] fp32 -> w1t2: kt-tiled, PRE-SWIZZLED bf16 layout.
//     (b) zero M_raw / den accumulators (stream-ordered before the gemm).
// ---------------------------------------------------------------------------
__global__ void k_prep(const float* __restrict__ W1, ushort* __restrict__ w1t2,
                       float* __restrict__ Mraw, float* __restrict__ dden) {
    int gid = blockIdx.x * 256 + threadIdx.x;          // 512*256 = 131072 threads
    if (gid < LDIM * DDIM) {
        int col = gid & 127, k = gid >> 7;             // W1 row-major: gid = k*128+col
        int kt = k >> 6, ko = k & 63;
        int cc = ko >> 3, kr = ko & 7;
        int ccs = cc ^ (col & 7);
        w1t2[kt * 8192 + col * 64 + ccs * 8 + kr] = f2b(W1[gid]);
    }
    if (gid < NBAGS * DDIM) Mraw[gid] = 0.0f;
    if (gid < NBAGS) dden[gid] = 0.0f;
}

// ---------------------------------------------------------------------------
// K1: H = relu(x@W1+b1) (stays in LDS);  a = (tanh(HWt+bt)*sigmoid(HWs+bs))@Wa+ba
// then w = exp(a) (no max needed: |a| <= ~5.7) and per-bag partial
// sums  Mraw[b][:] += sum w_i H_i,  den[b] += sum w_i  via atomics.
// 128x128 tile, BK=64, 4 waves (2x2), mfma_f32_16x16x32_bf16, linear staging,
// one-step software pipeline.
// ---------------------------------------------------------------------------
__global__ __launch_bounds__(256, 3) void k_fused_gemm(
    const float* __restrict__ x, const ushort* __restrict__ w1t2,
    const float* __restrict__ b1,
    const float* __restrict__ Wt, const float* __restrict__ bt,
    const float* __restrict__ Ws, const float* __restrict__ bs,
    const float* __restrict__ Wa, const float* __restrict__ ba,
    const int* __restrict__ idxs,
    float* __restrict__ Mraw, float* __restrict__ dden)
{
    __shared__ __align__(16) ushort sAB[16384];    // 32 KB: A tile | B tile, later sH
    __shared__ __align__(16) ushort sWtT[4096];    // Wt^T [32 f][128 d] bf16, swizzled
    __shared__ __align__(16) ushort sWsT[4096];    // Ws^T bf16, swizzled
    __shared__ float sb1[128];
    __shared__ float sbt[32], sbs[32], sWa[32];
    __shared__ float sw[128];                      // per-row softmax weight
    __shared__ int   sbag[128];                    // per-row bag id

    const int t    = threadIdx.x;
    const int lane = t & 63;
    const int wave = t >> 6;
    const int wr   = wave >> 1, wc = wave & 1;     // wave 64x64 sub-tile
    const int lq   = lane >> 4, lr = lane & 15;
    const int row0 = blockIdx.x * 128;

    // stage Wt^T / Ws^T as swizzled bf16 (once per block)
    for (int e = t; e < 4096; e += 256) {
        int d = e >> 5, f = e & 31;                // Wt row-major: e = d*32+f
        int byt = f * 256 + ((((d >> 3) ^ (f & 15))) << 4) + (d & 7) * 2;
        *(ushort*)((char*)sWtT + byt) = f2b(Wt[e]);
        *(ushort*)((char*)sWsT + byt) = f2b(Ws[e]);
    }
    if (t < 128) { sb1[t] = b1[t]; sbag[t] = idxs[row0 + t]; }
    if (t < 32)  { sbt[t] = bt[t]; sbs[t] = bs[t]; sWa[t] = Wa[t]; }
    const float ba0 = ba[0];

    f32x4 acc[4][4];
#pragma unroll
    for (int m = 0; m < 4; ++m)
#pragma unroll
        for (int n = 0; n < 4; ++n) acc[m][n] = 0;

    char* sA = (char*)sAB;
    char* sB = (char*)sAB + 16384;

    // ---- linear staging geometry ----
    const int arow  = t >> 4;                  // 0..15
    const int acol4 = (t & 15) * 4;            // fp32 col 0..60
    const float* xb = x + (size_t)(row0 + arow) * LDIM + acol4;
    const int a_base = (((acol4 >> 3) ^ (arow & 7)) << 4) + (acol4 & 7) * 2;
    const ushort* bb = w1t2 + t * 8;
    char* sBw = sB + t * 16;

    // prologue: load tile kt=0 into registers
    float4 av[8];
    bf16x8 bv[4];
#pragma unroll
    for (int j = 0; j < 8; ++j) av[j] = *(const float4*)(xb + j * (16 * LDIM));
#pragma unroll
    for (int jj = 0; jj < 4; ++jj) bv[jj] = *(const bf16x8*)(bb + jj * 2048);

    for (int kt = 0; kt < 16; ++kt) {
        __syncthreads();   // all waves done reading LDS of prev step

        // stage registers -> LDS (fp32 -> bf16 for A; B is a linear copy)
#pragma unroll
        for (int j = 0; j < 8; ++j) {
            float4 f = av[j];
            uint2 pk;
            pk.x = (unsigned)f2b(f.x) | ((unsigned)f2b(f.y) << 16);
            pk.y = (unsigned)f2b(f.z) | ((unsigned)f2b(f.w) << 16);
            *(uint2*)(sA + (arow + 16 * j) * 128 + a_base) = pk;
        }
#pragma unroll
        for (int jj = 0; jj < 4; ++jj)
            *(bf16x8*)(sBw + jj * 4096) = bv[jj];
        __syncthreads();

        // issue loads for kt+1: in flight during the MFMA phase
        if (kt < 15) {
            const float* xk = xb + (kt + 1) * 64;
#pragma unroll
            for (int j = 0; j < 8; ++j) av[j] = *(const float4*)(xk + j * (16 * LDIM));
            const ushort* bk = bb + (kt + 1) * 8192;
#pragma unroll
            for (int jj = 0; jj < 4; ++jj) bv[jj] = *(const bf16x8*)(bk + jj * 2048);
        }

#pragma unroll
        for (int kk = 0; kk < 2; ++kk) {
            bf16x8 aF[4], bF[4];
#pragma unroll
            for (int m = 0; m < 4; ++m) {
                int ra = wr * 64 + m * 16 + lr;    // A: row = lane%16
                aF[m] = *(const bf16x8*)(sA + ra * 128 + (((kk * 4 + lq) ^ (ra & 7)) << 4));
            }
#pragma unroll
            for (int n = 0; n < 4; ++n) {
                int cb = wc * 64 + n * 16 + lr;    // B: col = lane%16
                bF[n] = *(const bf16x8*)(sB + cb * 128 + (((kk * 4 + lq) ^ (cb & 7)) << 4));
            }
#pragma unroll
            for (int m = 0; m < 4; ++m)
#pragma unroll
                for (int n = 0; n < 4; ++n)
                    acc[m][n] = __builtin_amdgcn_mfma_f32_16x16x32_bf16(aF[m], bF[n], acc[m][n], 0, 0, 0);
        }
    }
    __syncthreads();   // K-loop LDS dead; reuse as sH

    // epilogue: bias + relu, bf16, into swizzled sH [128 rows][256 B], slot ^= row&15
    char* sH = (char*)sAB;
#pragma unroll
    for (int m = 0; m < 4; ++m) {
#pragma unroll
        for (int n = 0; n < 4; ++n) {
            const int colg = wc * 64 + n * 16 + lr;          // C/D: col = lane&15
            const float bias = sb1[colg];
#pragma unroll
            for (int r = 0; r < 4; ++r) {
                const int rowl = wr * 64 + m * 16 + lq * 4 + r; // C/D: row = (lane>>4)*4+reg
                float h = acc[m][n][r] + bias;
                h = fmaxf(h, 0.0f);
                *(ushort*)(sH + rowl * 256 + (((colg >> 3) ^ (rowl & 15)) << 4) + (colg & 7) * 2) = f2b(h);
            }
        }
    }
    __syncthreads();

    // ---- score pass via MFMA: each wave owns 32 rows (wave*32 .. wave*32+31)
    {
        f32x4 at_[2][2], as_[2][2];
#pragma unroll
        for (int m = 0; m < 2; ++m)
#pragma unroll
            for (int n = 0; n < 2; ++n) { at_[m][n] = 0; as_[m][n] = 0; }

        const char* cWtT = (const char*)sWtT;
        const char* cWsT = (const char*)sWsT;
#pragma unroll
        for (int kk = 0; kk < 4; ++kk) {
            bf16x8 aH[2], bT[2], bS[2];
            const int slot = kk * 4 + lq;
#pragma unroll
            for (int m = 0; m < 2; ++m) {
                const int ra = wave * 32 + m * 16 + lr;
                aH[m] = *(const bf16x8*)(sH + ra * 256 + ((slot ^ (ra & 15)) << 4));
            }
#pragma unroll
            for (int n = 0; n < 2; ++n) {
                const int f = n * 16 + lr;
                bT[n] = *(const bf16x8*)(cWtT + f * 256 + ((slot ^ (f & 15)) << 4));
                bS[n] = *(const bf16x8*)(cWsT + f * 256 + ((slot ^ (f & 15)) << 4));
            }
#pragma unroll
            for (int m = 0; m < 2; ++m)
#pragma unroll
                for (int n = 0; n < 2; ++n) {
                    at_[m][n] = __builtin_amdgcn_mfma_f32_16x16x32_bf16(aH[m], bT[n], at_[m][n], 0, 0, 0);
                    as_[m][n] = __builtin_amdgcn_mfma_f32_16x16x32_bf16(aH[m], bS[n], as_[m][n], 0, 0, 0);
                }
        }

        // gated combine + row-reduce over 32 F-cols -> w = exp(a)
#pragma unroll
        for (int m = 0; m < 2; ++m) {
#pragma unroll
            for (int r = 0; r < 4; ++r) {
                float s = 0.f;
#pragma unroll
                for (int n = 0; n < 2; ++n) {
                    const int f = n * 16 + lr;
                    float tv = tanhf(at_[m][n][r] + sbt[f]);
                    float sg = 1.0f / (1.0f + __expf(-(as_[m][n][r] + sbs[f])));
                    s += tv * sg * sWa[f];
                }
                s += __shfl_xor(s, 1);
                s += __shfl_xor(s, 2);
                s += __shfl_xor(s, 4);
                s += __shfl_xor(s, 8);
                if (lr == 0)
                    sw[wave * 32 + m * 16 + lq * 4 + r] = __expf(s + ba0);
            }
        }
    }
    __syncthreads();

    // ---- per-bag partial reduce from LDS, atomically into Mraw/den.
    // 256 threads: d = t&127, half = t>>7 covers rows [half*64, half*64+64).
    {
        const int d = t & 127, half = t >> 7;
        const int r0 = half * 64;
        float accv = 0.f, accw = 0.f;
        int curbag = sbag[r0];
        for (int r = 0; r < 64; ++r) {
            const int rr = r0 + r;
            const int bg = sbag[rr];
            if (bg != curbag) {
                atomicAdd(&Mraw[curbag * 128 + d], accv);
                if (d == 0) atomicAdd(&dden[curbag], accw);
                accv = 0.f; accw = 0.f; curbag = bg;
            }
            const float w = sw[rr];
            const ushort hv = *(const ushort*)(sH + rr * 256 + ((((d >> 3) ^ (rr & 15))) << 4) + (d & 7) * 2);
            accv += w * b2f(hv);
            accw += w;
        }
        atomicAdd(&Mraw[curbag * 128 + d], accv);
        if (d == 0) atomicAdd(&dden[curbag], accw);
    }
}

// ---------------------------------------------------------------------------
// K2: finalize — M = Mraw/den, projector + L2 normalize. One block per bag.
// ---------------------------------------------------------------------------
__global__ __launch_bounds__(128) void k_final(
    const float* __restrict__ Mraw, const float* __restrict__ dden,
    const float* __restrict__ Wp, const float* __restrict__ bp,
    float* __restrict__ out)
{
    __shared__ float sM[128];
    const int b = blockIdx.x, t = threadIdx.x;
    const float den = dden[b];
    const float inv_den = den > 0.f ? 1.0f / den : 0.0f;

    float m = Mraw[b * 128 + t] * inv_den;
    sM[t] = m;
    out[b * 128 + t] = m;
    __syncthreads();

    if (t < 32) {
        float p = bp[t];
        for (int d = 0; d < 128; ++d) p += sM[d] * Wp[d * 32 + t];
        float ss = p * p;
#pragma unroll
        for (int mm = 1; mm < 32; mm <<= 1) ss += __shfl_xor(ss, mm);
        float nrm = sqrtf(ss);
        out[32768 + b * 32 + t] = p / fmaxf(nrm, 1e-12f);
    }
}

// ---------------------------------------------------------------------------
extern "C" void kernel_launch(void* const* d_in, const int* in_sizes, int n_in,
                              void* d_out, int out_size, void* d_ws, size_t ws_size,
                              hipStream_t stream)
{
    const float* x  = (const float*)d_in[0];
    const int*   idxs = (const int*)d_in[1];
    const float* W1 = (const float*)d_in[2];
    const float* b1 = (const float*)d_in[3];
    const float* Wt = (const float*)d_in[4];
    const float* bt = (const float*)d_in[5];
    const float* Ws = (const float*)d_in[6];
    const float* bs = (const float*)d_in[7];
    const float* Wa = (const float*)d_in[8];
    const float* ba = (const float*)d_in[9];
    const float* Wp = (const float*)d_in[10];
    const float* bp = (const float*)d_in[11];
    float* out = (float*)d_out;

    // ws layout: Mraw f32 [256][128] = 128 KB | den f32 [256] = 1 KB | w1t2 bf16 256 KB
    char* ws = (char*)d_ws;
    float*  Mraw = (float*)ws;
    float*  dden = (float*)(ws + 131072);
    ushort* w1t2 = (ushort*)(ws + 132096);

    k_prep<<<512, 256, 0, stream>>>(W1, w1t2, Mraw, dden);
    k_fused_gemm<<<2048, 256, 0, stream>>>(x, w1t2, b1, Wt, bt, Ws, bs, Wa, ba, idxs, Mraw, dden);
    k_final<<<NBAGS, 128, 0, stream>>>(Mraw, dden, Wp, bp, out);
}